// Round 16
// baseline (146.149 us; speedup 1.0000x reference)
//
#include <hip/hip_runtime.h>

#define B_ 2
#define N_ 2048
#define C_ 1024
#define H_ 16
#define D_ 64
#define M_ (B_*N_)   // 4096
#define LOG2E 1.44269504088896340736f

typedef __bf16 bf16x8 __attribute__((ext_vector_type(8)));
typedef float  f32x4  __attribute__((ext_vector_type(4)));
typedef float  f32x16 __attribute__((ext_vector_type(16)));
typedef unsigned short u16;

#define MFMA16(a, b, c) __builtin_amdgcn_mfma_f32_16x16x32_bf16(a, b, c, 0, 0, 0)
#define MFMA32(a, b, c) __builtin_amdgcn_mfma_f32_32x32x16_bf16(a, b, c, 0, 0, 0)

__device__ __forceinline__ u16 f2b(float f) {
    union { float f; unsigned int u; } v; v.f = f;
    unsigned int r = (v.u + 0x7fffu + ((v.u >> 16) & 1u)) >> 16;
    return (u16)r;
}
__device__ __forceinline__ float b2f(u16 h) {
    union { unsigned int u; float f; } v; v.u = ((unsigned int)h) << 16;
    return v.f;
}
// raw 2^x — args bounded in [-35, 0]: no denorm fixup needed (libm exp2f adds ~4 ops)
__device__ __forceinline__ float exp2_raw(float x) {
    float r;
    asm("v_exp_f32 %0, %1" : "=v"(r) : "v"(x));
    return r;
}
__device__ __forceinline__ void gload16(const void* g, void* lds) {
    __builtin_amdgcn_global_load_lds(
        (const __attribute__((address_space(1))) unsigned int*)g,
        (__attribute__((address_space(3))) unsigned int*)lds, 16, 0, 0);
}

// ---------------- fused prep: x->bf16 (2048 blk) | WqkvT (768) | WoutT (256) ----------------
__global__ __launch_bounds__(256) void prep(
    const float* __restrict__ x, const float* __restrict__ Wqkv,
    const float* __restrict__ Wout, u16* __restrict__ xb,
    u16* __restrict__ wqkvt, u16* __restrict__ woutt)
{
    __shared__ u16 T[64][72];
    const int t = threadIdx.x;
    const int bid = blockIdx.x;
    if (bid < 2048) {
        int i = bid * 256 + t;
        float4 a = *(const float4*)(x + (size_t)i * 8);
        float4 b = *(const float4*)(x + (size_t)i * 8 + 4);
        u16 tmp[8] = { f2b(a.x), f2b(a.y), f2b(a.z), f2b(a.w),
                       f2b(b.x), f2b(b.y), f2b(b.z), f2b(b.w) };
        *(uint4*)(xb + (size_t)i * 8) = *(uint4*)tmp;
        return;
    }
    const float* W; u16* Wt; int K, N, blk;
    if (bid < 2048 + 768) { W = Wqkv; Wt = wqkvt; K = 1024; N = 3072; blk = bid - 2048; }
    else                  { W = Wout; Wt = woutt; K = 1024; N = 1024; blk = bid - 2816; }
    const int ntiles = N >> 6;
    const int kt = blk / ntiles, ntl = blk % ntiles;
#pragma unroll
    for (int u = 0; u < 2; ++u) {
        int f = t + u * 256;
        int r = f >> 3, c = f & 7;
        const float* p = W + (size_t)(kt * 64 + r) * N + ntl * 64 + c * 8;
        float4 a = *(const float4*)p;
        float4 b = *(const float4*)(p + 4);
        u16 tmp[8] = { f2b(a.x), f2b(a.y), f2b(a.z), f2b(a.w),
                       f2b(b.x), f2b(b.y), f2b(b.z), f2b(b.w) };
        *(uint4*)&T[r][c * 8] = *(uint4*)tmp;
    }
    __syncthreads();
    int n = t >> 2;
    u16 tmp[16];
#pragma unroll
    for (int i = 0; i < 16; ++i) tmp[i] = T[(t & 3) * 16 + i][n];
    u16* o = Wt + (size_t)(ntl * 64 + n) * K + kt * 64 + (t & 3) * 16;
    *(uint4*)o       = *(uint4*)&tmp[0];
    *(uint4*)(o + 8) = *(uint4*)&tmp[8];
}

// ---------------- GEMM bf16 MFMA (128x128 tile): qkv projection ----------------
// grid (24,32); XCD-chunked swizzle: each XCD owns 4 contiguous bm rows (A-panel L2 reuse)
__global__ __launch_bounds__(256) void gemm_bf16(
    const u16* __restrict__ A, const u16* __restrict__ Bt,
    const float* __restrict__ bias, void* __restrict__ Cout,
    int M, int N, int K, int bf16out)
{
    __shared__ u16 Al[2][128 * 32];
    __shared__ u16 Bl[2][128 * 32];
    const int t = threadIdx.x, l = t & 63, w = t >> 6;
    const int wr = w >> 1, wc = w & 1;
    const int flat = blockIdx.y * 24 + blockIdx.x;          // dispatch order (x fastest)
    const int orig = (flat & 7) * 96 + (flat >> 3);         // 768 blocks, 96/XCD
    const int bm = (orig / 24) * 128, bn = (orig % 24) * 128;

    f32x4 acc[4][4];
#pragma unroll
    for (int i = 0; i < 4; ++i)
#pragma unroll
        for (int j = 0; j < 4; ++j) acc[i][j] = (f32x4){0.f, 0.f, 0.f, 0.f};

    const int srow = (l >> 2);
    const int schunk = (l & 3) ^ ((l >> 2) & 3);

    auto stage = [&](int buf, int k0) {
#pragma unroll
        for (int u = 0; u < 2; ++u) {
            int p = w * 2 + u;
            int r = p * 16 + srow;
            gload16(A + (size_t)(bm + r) * K + k0 + schunk * 8, &Al[buf][p * 512]);
            gload16(Bt + (size_t)(bn + r) * K + k0 + schunk * 8, &Bl[buf][p * 512]);
        }
    };

    stage(0, 0);
    const int NT = K / 32;
    const int g = l >> 4;
    for (int tt = 0; tt < NT; ++tt) {
        __syncthreads();
        if (tt + 1 < NT) stage((tt + 1) & 1, (tt + 1) * 32);
        const u16* al = &Al[tt & 1][0];
        const u16* bl = &Bl[tt & 1][0];
        bf16x8 af[4], bf[4];
#pragma unroll
        for (int mb = 0; mb < 4; ++mb) {
            int r = wr * 64 + mb * 16 + (l & 15);
            af[mb] = *(const bf16x8*)(al + r * 32 + ((g ^ (r & 3)) << 3));
            int n = wc * 64 + mb * 16 + (l & 15);
            bf[mb] = *(const bf16x8*)(bl + n * 32 + ((g ^ (n & 3)) << 3));
        }
        __builtin_amdgcn_s_setprio(1);
#pragma unroll
        for (int mb = 0; mb < 4; ++mb)
#pragma unroll
            for (int nb = 0; nb < 4; ++nb)
                acc[mb][nb] = MFMA16(af[mb], bf[nb], acc[mb][nb]);
        __builtin_amdgcn_s_setprio(0);
    }

#pragma unroll
    for (int mb = 0; mb < 4; ++mb) {
        int row = bm + wr * 64 + mb * 16 + (l >> 4) * 4;
#pragma unroll
        for (int nb = 0; nb < 4; ++nb) {
            int col = bn + wc * 64 + nb * 16 + (l & 15);
            float bv = bias[col];
#pragma unroll
            for (int r = 0; r < 4; ++r) {
                float v = acc[mb][nb][r] + bv;
                if (bf16out) ((u16*)Cout)[(size_t)(row + r) * N + col] = f2b(v);
                else        ((float*)Cout)[(size_t)(row + r) * N + col] = v;
            }
        }
    }
}

// ---------------- GEMM bf16 MFMA (64x64 tile): output projection ----------------
// grid (16,64) = 1024 blocks -> 4 blocks/CU. XCD-chunked: 8 bm rows per XCD.
__global__ __launch_bounds__(256) void gemm64(
    const u16* __restrict__ A, const u16* __restrict__ Bt,
    const float* __restrict__ bias, float* __restrict__ Cout,
    int M, int N, int K)
{
    __shared__ u16 Al[2][64 * 32];
    __shared__ u16 Bl[2][64 * 32];
    const int t = threadIdx.x, l = t & 63, w = t >> 6;
    const int wr = w >> 1, wc = w & 1;
    const int flat = blockIdx.y * 16 + blockIdx.x;
    const int orig = (flat & 7) * 128 + (flat >> 3);        // 1024 blocks, 128/XCD
    const int bm = (orig >> 4) * 64, bn = (orig & 15) * 64;

    f32x4 acc[2][2];
#pragma unroll
    for (int i = 0; i < 2; ++i)
#pragma unroll
        for (int j = 0; j < 2; ++j) acc[i][j] = (f32x4){0.f, 0.f, 0.f, 0.f};

    const int srow = (l >> 2);
    const int schunk = (l & 3) ^ ((l >> 2) & 3);

    auto stage = [&](int buf, int k0) {
        int r = w * 16 + srow;
        gload16(A + (size_t)(bm + r) * K + k0 + schunk * 8, &Al[buf][w * 512]);
        gload16(Bt + (size_t)(bn + r) * K + k0 + schunk * 8, &Bl[buf][w * 512]);
    };

    stage(0, 0);
    const int NT = K / 32;
    const int g = l >> 4;
    for (int tt = 0; tt < NT; ++tt) {
        __syncthreads();
        if (tt + 1 < NT) stage((tt + 1) & 1, (tt + 1) * 32);
        const u16* al = &Al[tt & 1][0];
        const u16* bl = &Bl[tt & 1][0];
        bf16x8 af[2], bf[2];
#pragma unroll
        for (int mb = 0; mb < 2; ++mb) {
            int r = wr * 32 + mb * 16 + (l & 15);
            af[mb] = *(const bf16x8*)(al + r * 32 + ((g ^ (r & 3)) << 3));
            int n = wc * 32 + mb * 16 + (l & 15);
            bf[mb] = *(const bf16x8*)(bl + n * 32 + ((g ^ (n & 3)) << 3));
        }
        __builtin_amdgcn_s_setprio(1);
#pragma unroll
        for (int mb = 0; mb < 2; ++mb)
#pragma unroll
            for (int nb = 0; nb < 2; ++nb)
                acc[mb][nb] = MFMA16(af[mb], bf[nb], acc[mb][nb]);
        __builtin_amdgcn_s_setprio(0);
    }

#pragma unroll
    for (int mb = 0; mb < 2; ++mb) {
        int row = bm + wr * 32 + mb * 16 + (l >> 4) * 4;
#pragma unroll
        for (int nb = 0; nb < 2; ++nb) {
            int col = bn + wc * 32 + nb * 16 + (l & 15);
            float bv = bias[col];
#pragma unroll
            for (int r = 0; r < 4; ++r)
                Cout[(size_t)(row + r) * N + col] = acc[mb][nb][r] + bv;
        }
    }
}

// ---------------- fused: vectorized RMSNorm q,k (1024 blk) | V transpose (1024 blk) ----------------
__global__ __launch_bounds__(256) void rms_vt(
    const u16* __restrict__ qkvb, const float* __restrict__ gq,
    const float* __restrict__ gk, u16* __restrict__ qb, u16* __restrict__ kb,
    u16* __restrict__ vt)
{
    __shared__ u16 T[64][72];
    const int t = threadIdx.x;
    if (blockIdx.x < 1024) {
        const int row = blockIdx.x * 4 + (t >> 6), lane = t & 63;
        const u16* base = qkvb + (size_t)row * 3072;
        const int d0 = (lane & 7) * 8;
#pragma unroll
        for (int i = 0; i < 4; ++i) {
            int off = i * 512 + lane * 8;
            uint4 xv = *(const uint4*)(base + off);
            const u16* e = (const u16*)&xv;
            float f[8]; float ss = 0.f;
#pragma unroll
            for (int j = 0; j < 8; ++j) { f[j] = b2f(e[j]); ss += f[j] * f[j]; }
            ss += __shfl_xor(ss, 1, 64);
            ss += __shfl_xor(ss, 2, 64);
            ss += __shfl_xor(ss, 4, 64);
            float inv = rsqrtf(fmaxf(ss, 1e-24f));
            int vec = i * 8 + (lane >> 3);
            int isK = vec >> 4, h = vec & 15;
            const float* gm = (isK ? gk : gq) + h * 64 + d0;
            float4 g0 = *(const float4*)gm;
            float4 g1 = *(const float4*)(gm + 4);
            float gg[8] = { g0.x, g0.y, g0.z, g0.w, g1.x, g1.y, g1.z, g1.w };
            float scale = isK ? 8.0f : LOG2E;
            u16 ov[8];
#pragma unroll
            for (int j = 0; j < 8; ++j) ov[j] = f2b(f[j] * inv * gg[j] * scale);
            u16* dst = (isK ? kb : qb) + (size_t)row * 1024 + h * 64 + d0;
            *(uint4*)dst = *(uint4*)ov;
        }
        return;
    }
    const int blk = blockIdx.x - 1024;
    const int nt = blk & 31;
    const int bh = blk >> 5;
    const int b = bh >> 4, h = bh & 15;
#pragma unroll
    for (int u = 0; u < 2; ++u) {
        int f = t + u * 256;
        int n = f >> 3, c = f & 7;
        uint4 v = *(const uint4*)(qkvb + (size_t)(b * 2048 + nt * 64 + n) * 3072 + 2048 + h * 64 + c * 8);
        *(uint4*)&T[n][c * 8] = v;
    }
    __syncthreads();
    int d = t >> 2;
    u16 tmp[16];
#pragma unroll
    for (int i = 0; i < 16; ++i) tmp[i] = T[(t & 3) * 16 + i][d];
    u16* o = vt + ((size_t)bh * 64 + d) * 2048 + nt * 64 + (t & 3) * 16;
    *(uint4*)o       = *(uint4*)&tmp[0];
    *(uint4*)(o + 8) = *(uint4*)&tmp[8];
}

// ---------------- Flash attention: KV-split x4, fixed max, BARRIER-FREE wave-private ----------------
// Each wave owns private K/V double-buffers (16KB/wave, 64KB/block -> 2 blocks/CU by LDS).
// No __syncthreads/s_barrier in the loop: per-wave counted vmcnt(8) only (own stage in flight).
// Same-wave gload_lds -> ds_read visibility = vmcnt retirement. sched_barrier per rule #18.
// KVBLK=32 compute mapping verified in r14/r15 (pi-permute, fixed V swizzle (row>>1)&3).
__global__ __launch_bounds__(256, 2) void attn_mfma(
    const u16* __restrict__ qb, const u16* __restrict__ kbuf,
    const u16* __restrict__ vt, u16* __restrict__ op012, u16* __restrict__ op3,
    float* __restrict__ lsums)
{
    __shared__ u16 Kl[4][2][2048];   // [wave][dbuf][32 k-rows x 64 d]
    __shared__ u16 Vl[4][2][2048];   // [wave][dbuf][64 d-rows x 32 n]

    const int t = threadIdx.x, l = t & 63, w = t >> 6;
    const int hi = l >> 5, lq = l & 31;
    const int orig = ((blockIdx.x & 7) << 8) | (blockIdx.x >> 3);   // XCD-chunked
    const int qt = orig & 15;
    const int s  = (orig >> 4) & 3;        // KV split 0..3 (512 rows each)
    const int bh = orig >> 6;
    const int b = bh >> 4, h = bh & 15;
    const int bq = bh * 16 + qt;
    const int kv0 = s * 512;

    const int qrow = b * 2048 + qt * 128 + w * 32 + lq;
    bf16x8 qf[4];
#pragma unroll
    for (int ds = 0; ds < 4; ++ds)
        qf[ds] = *(const bf16x8*)(qb + (size_t)qrow * 1024 + h * 64 + ds * 16 + hi * 8);

    f32x16 O0, O1;
#pragma unroll
    for (int r = 0; r < 16; ++r) { O0[r] = 0.f; O1[r] = 0.f; }
    float lsum = 0.f;

    auto stage = [&](int buf, int kt) {
        // K: 32 rows x 64 d = 4KB, 4x gload16 (1KB each); pi-permuted source row
#pragma unroll
        for (int i = 0; i < 4; ++i) {
            int row = i * 8 + (l >> 3);
            int c = (l & 7) ^ (row & 7);
            int bb = (row >> 2) & 3;
            int grow = (bb == 1 || bb == 2) ? (row ^ 12) : row;
            gload16(kbuf + (size_t)(b * 2048 + kv0 + kt * 32 + grow) * 1024 + h * 64 + c * 8,
                    &Kl[w][buf][i * 512]);
        }
        // V: 64 d-rows x 32 n = 4KB, 4x gload16; chunk swizzle (row>>1)&3
#pragma unroll
        for (int i = 0; i < 4; ++i) {
            int row = i * 16 + (l >> 2);
            int c = (l & 3) ^ ((row >> 1) & 3);
            gload16(vt + ((size_t)bh * 64 + row) * 2048 + kv0 + kt * 32 + c * 8,
                    &Vl[w][buf][i * 512]);
        }
    };

    stage(0, 0);
    for (int kt = 0; kt < 16; ++kt) {
        if (kt + 1 < 16) {
            stage((kt + 1) & 1, kt + 1);
            asm volatile("s_waitcnt vmcnt(8)" ::: "memory");   // own stage(kt) landed
        } else {
            asm volatile("s_waitcnt vmcnt(0)" ::: "memory");
        }
        __builtin_amdgcn_sched_barrier(0);
        const u16* kl = &Kl[w][kt & 1][0];
        const u16* vl = &Vl[w][kt & 1][0];

        // S^T = K.Q^T (rows = pi-permuted k 0..31, cols = q on lane&31)
        f32x16 S;
#pragma unroll
        for (int r = 0; r < 16; ++r) S[r] = 0.f;
        __builtin_amdgcn_s_setprio(1);
#pragma unroll
        for (int ds = 0; ds < 4; ++ds) {
            int ch = ds * 2 + hi;
            bf16x8 kf = *(const bf16x8*)(kl + lq * 64 + ((ch ^ (lq & 7)) << 3));
            S = MFMA32(kf, qf[ds], S);
        }
        __builtin_amdgcn_s_setprio(0);

        // P = 2^(S - 12), fixed max (Cauchy-Schwarz bound, RMS-normed q,k)
#pragma unroll
        for (int r = 0; r < 16; ++r) S[r] = exp2_raw(S[r] - 12.0f);
        float sp[16];
#pragma unroll
        for (int r = 0; r < 16; ++r) sp[r] = S[r];
#pragma unroll
        for (int s2 = 8; s2 > 0; s2 >>= 1)
#pragma unroll
            for (int r = 0; r < 8; ++r)
                if (r < s2) sp[r] += sp[r + s2];
        lsum += sp[0];

        // pack P: pi-permutation -> straight cvt_pk of registers
        bf16x8 pa[2];
        {
            unsigned x[8];
#pragma unroll
            for (int i = 0; i < 8; ++i)
                asm("v_cvt_pk_bf16_f32 %0, %1, %2"
                    : "=v"(x[i]) : "v"(S[2 * i]), "v"(S[2 * i + 1]));
            union { unsigned wv[4]; bf16x8 v; } uu;
            uu.wv[0] = x[0]; uu.wv[1] = x[1]; uu.wv[2] = x[2]; uu.wv[3] = x[3];
            pa[0] = uu.v;
            uu.wv[0] = x[4]; uu.wv[1] = x[5]; uu.wv[2] = x[6]; uu.wv[3] = x[7];
            pa[1] = uu.v;
        }

        // O^T += V^T @ P^T  (A = V^T d-rows from Vl[64][32], B = pa)
        __builtin_amdgcn_s_setprio(1);
#pragma unroll
        for (int ks = 0; ks < 2; ++ks) {
            int ch = ks * 2 + hi;
            bf16x8 vf0 = *(const bf16x8*)(vl + lq * 32 + ((ch ^ ((lq >> 1) & 3)) << 3));
            bf16x8 vf1 = *(const bf16x8*)(vl + (lq + 32) * 32 + ((ch ^ ((lq >> 1) & 3)) << 3));
            O0 = MFMA32(vf0, pa[ks], O0);
            O1 = MFMA32(vf1, pa[ks], O1);
        }
        __builtin_amdgcn_s_setprio(0);
    }

    // epilogue: unnormalized partial O (bf16) + lsum (f32, one lane per q-row)
    u16* ob = ((s == 3) ? op3 : op012 + (size_t)s * 4194304)
              + ((size_t)bq * 128 + (w * 32 + lq)) * 64;
    f32x16 Ox[2] = { O0, O1 };
#pragma unroll
    for (int db = 0; db < 2; ++db) {
#pragma unroll
        for (int a = 0; a < 4; ++a) {
            int d0 = a * 8 + hi * 4 + db * 32;
            unsigned long long pk = 0;
#pragma unroll
            for (int bb = 0; bb < 4; ++bb)
                pk |= (unsigned long long)f2b(Ox[db][a * 4 + bb]) << (16 * bb);
            *(unsigned long long*)(ob + d0) = pk;
        }
    }
    float ltot = lsum + __shfl_xor(lsum, 32, 64);
    if (hi == 0)
        lsums[((size_t)s * 512 + bq) * 128 + w * 32 + lq] = ltot;
}

// ---------------- combine the 4 KV-splits (shared m -> plain weighted sum) ----------------
__global__ __launch_bounds__(256) void attn_combine(
    const u16* __restrict__ op012, const u16* __restrict__ op3,
    const float* __restrict__ lsums, u16* __restrict__ attnb)
{
    const int t = threadIdx.x;
    const int bq = blockIdx.x >> 1, qh = blockIdx.x & 1;
    const int bh = bq >> 4, qt = bq & 15;
    const int b = bh >> 4, h = bh & 15;
    const int q = qh * 64 + (t >> 2), dseg = (t & 3) * 16;

    float l = 0.f;
#pragma unroll
    for (int sp = 0; sp < 4; ++sp)
        l += lsums[((size_t)sp * 512 + bq) * 128 + q];
    float linv = 1.0f / l;

    float acc[16];
#pragma unroll
    for (int e = 0; e < 16; ++e) acc[e] = 0.f;
#pragma unroll
    for (int sp = 0; sp < 4; ++sp) {
        const u16* p = ((sp == 3) ? op3 : op012 + (size_t)sp * 4194304)
                       + ((size_t)bq * 128 + q) * 64 + dseg;
        uint4 x0 = *(const uint4*)p;
        uint4 x1 = *(const uint4*)(p + 8);
        const u16* e0 = (const u16*)&x0;
        const u16* e1 = (const u16*)&x1;
#pragma unroll
        for (int e = 0; e < 8; ++e) { acc[e] += b2f(e0[e]); acc[8 + e] += b2f(e1[e]); }
    }
    u16 ov[16];
#pragma unroll
    for (int e = 0; e < 16; ++e) ov[e] = f2b(acc[e] * linv);
    u16* o = attnb + (size_t)(b * 2048 + qt * 128 + q) * 1024 + h * 64 + dseg;
    *(uint4*)o       = *(uint4*)&ov[0];
    *(uint4*)(o + 8) = *(uint4*)&ov[8];
}

extern "C" void kernel_launch(void* const* d_in, const int* in_sizes, int n_in,
                              void* d_out, int out_size, void* d_ws, size_t ws_size,
                              hipStream_t stream)
{
    const float* x    = (const float*)d_in[0];
    const float* Wqkv = (const float*)d_in[1];
    const float* bqkv = (const float*)d_in[2];
    const float* gq   = (const float*)d_in[3];
    const float* gk   = (const float*)d_in[4];
    const float* Wout = (const float*)d_in[5];
    const float* bout = (const float*)d_in[6];
    float* out = (float*)d_out;

    char* ws = (char*)d_ws;
    u16* xb     = (u16*)(ws);                 // prep -> gemm1
    u16* op3    = (u16*)(ws);                 // attn -> combine   (xb dead)
    u16* wqkvt  = (u16*)(ws + ( 8u << 20));   // prep -> gemm1
    float* lsums= (float*)(ws + ( 8u << 20)); // attn -> combine   (wqkvt dead)
    u16* woutt  = (u16*)(ws + (14u << 20));   // prep -> gemm2
    u16* qkvb   = (u16*)(ws + (16u << 20));   // gemm1 -> rms_vt
    u16* op012  = (u16*)(ws + (16u << 20));   // attn -> combine   (qkvb dead)
    u16* qbuf   = (u16*)(ws + (40u << 20));   // rms_vt -> attn
    u16* attnb  = (u16*)(ws + (40u << 20));   // combine -> gemm2  (qbuf dead)
    u16* kbuf   = (u16*)(ws + (48u << 20));   // rms_vt -> attn
    u16* vtb    = (u16*)(ws + (56u << 20));   // rms_vt -> attn

    prep<<<3072, 256, 0, stream>>>(x, Wqkv, Wout, xb, wqkvt, woutt);
    gemm_bf16<<<dim3(24, 32), 256, 0, stream>>>(xb, wqkvt, bqkv, qkvb, M_, 3072, 1024, 1);
    rms_vt<<<2048, 256, 0, stream>>>(qkvb, gq, gk, qbuf, kbuf, vtb);
    attn_mfma<<<2048, 256, 0, stream>>>(qbuf, kbuf, vtb, op012, op3, lsums);
    attn_combine<<<1024, 256, 0, stream>>>(op012, op3, lsums, attnb);
    gemm64<<<dim3(16, 64), 256, 0, stream>>>(attnb, woutt, bout, out, M_, 1024, 1024);
}

// Round 17
// 127.961 us; speedup vs baseline: 1.1421x; 1.1421x over previous
//
#include <hip/hip_runtime.h>

#define B_ 2
#define N_ 2048
#define C_ 1024
#define H_ 16
#define D_ 64
#define M_ (B_*N_)   // 4096
#define LOG2E 1.44269504088896340736f

typedef __bf16 bf16x8 __attribute__((ext_vector_type(8)));
typedef float  f32x4  __attribute__((ext_vector_type(4)));
typedef float  f32x16 __attribute__((ext_vector_type(16)));
typedef unsigned short u16;

#define MFMA16(a, b, c) __builtin_amdgcn_mfma_f32_16x16x32_bf16(a, b, c, 0, 0, 0)
#define MFMA32(a, b, c) __builtin_amdgcn_mfma_f32_32x32x16_bf16(a, b, c, 0, 0, 0)

__device__ __forceinline__ u16 f2b(float f) {
    union { float f; unsigned int u; } v; v.f = f;
    unsigned int r = (v.u + 0x7fffu + ((v.u >> 16) & 1u)) >> 16;
    return (u16)r;
}
__device__ __forceinline__ float b2f(u16 h) {
    union { unsigned int u; float f; } v; v.u = ((unsigned int)h) << 16;
    return v.f;
}
// raw 2^x — args bounded in [-35, 0]: no denorm fixup needed (libm exp2f adds ~4 ops)
__device__ __forceinline__ float exp2_raw(float x) {
    float r;
    asm("v_exp_f32 %0, %1" : "=v"(r) : "v"(x));
    return r;
}
__device__ __forceinline__ void gload16(const void* g, void* lds) {
    __builtin_amdgcn_global_load_lds(
        (const __attribute__((address_space(1))) unsigned int*)g,
        (__attribute__((address_space(3))) unsigned int*)lds, 16, 0, 0);
}

// ---------------- fused prep: x->bf16 (2048 blk) | WqkvT (768) | WoutT (256) ----------------
__global__ __launch_bounds__(256) void prep(
    const float* __restrict__ x, const float* __restrict__ Wqkv,
    const float* __restrict__ Wout, u16* __restrict__ xb,
    u16* __restrict__ wqkvt, u16* __restrict__ woutt)
{
    __shared__ u16 T[64][72];
    const int t = threadIdx.x;
    const int bid = blockIdx.x;
    if (bid < 2048) {
        int i = bid * 256 + t;
        float4 a = *(const float4*)(x + (size_t)i * 8);
        float4 b = *(const float4*)(x + (size_t)i * 8 + 4);
        u16 tmp[8] = { f2b(a.x), f2b(a.y), f2b(a.z), f2b(a.w),
                       f2b(b.x), f2b(b.y), f2b(b.z), f2b(b.w) };
        *(uint4*)(xb + (size_t)i * 8) = *(uint4*)tmp;
        return;
    }
    const float* W; u16* Wt; int K, N, blk;
    if (bid < 2048 + 768) { W = Wqkv; Wt = wqkvt; K = 1024; N = 3072; blk = bid - 2048; }
    else                  { W = Wout; Wt = woutt; K = 1024; N = 1024; blk = bid - 2816; }
    const int ntiles = N >> 6;
    const int kt = blk / ntiles, ntl = blk % ntiles;
#pragma unroll
    for (int u = 0; u < 2; ++u) {
        int f = t + u * 256;
        int r = f >> 3, c = f & 7;
        const float* p = W + (size_t)(kt * 64 + r) * N + ntl * 64 + c * 8;
        float4 a = *(const float4*)p;
        float4 b = *(const float4*)(p + 4);
        u16 tmp[8] = { f2b(a.x), f2b(a.y), f2b(a.z), f2b(a.w),
                       f2b(b.x), f2b(b.y), f2b(b.z), f2b(b.w) };
        *(uint4*)&T[r][c * 8] = *(uint4*)tmp;
    }
    __syncthreads();
    int n = t >> 2;
    u16 tmp[16];
#pragma unroll
    for (int i = 0; i < 16; ++i) tmp[i] = T[(t & 3) * 16 + i][n];
    u16* o = Wt + (size_t)(ntl * 64 + n) * K + kt * 64 + (t & 3) * 16;
    *(uint4*)o       = *(uint4*)&tmp[0];
    *(uint4*)(o + 8) = *(uint4*)&tmp[8];
}

// ---------------- GEMM bf16 MFMA (128x128 tile): qkv projection ----------------
// grid (24,32); XCD-chunked swizzle. No setprio: m190 shows it's negative on
// barrier-synced lockstep GEMM structures (T5 needs a phase-split to pay).
__global__ __launch_bounds__(256) void gemm_bf16(
    const u16* __restrict__ A, const u16* __restrict__ Bt,
    const float* __restrict__ bias, void* __restrict__ Cout,
    int M, int N, int K, int bf16out)
{
    __shared__ u16 Al[2][128 * 32];
    __shared__ u16 Bl[2][128 * 32];
    const int t = threadIdx.x, l = t & 63, w = t >> 6;
    const int wr = w >> 1, wc = w & 1;
    const int flat = blockIdx.y * 24 + blockIdx.x;          // dispatch order (x fastest)
    const int orig = (flat & 7) * 96 + (flat >> 3);         // 768 blocks, 96/XCD
    const int bm = (orig / 24) * 128, bn = (orig % 24) * 128;

    f32x4 acc[4][4];
#pragma unroll
    for (int i = 0; i < 4; ++i)
#pragma unroll
        for (int j = 0; j < 4; ++j) acc[i][j] = (f32x4){0.f, 0.f, 0.f, 0.f};

    const int srow = (l >> 2);
    const int schunk = (l & 3) ^ ((l >> 2) & 3);

    auto stage = [&](int buf, int k0) {
#pragma unroll
        for (int u = 0; u < 2; ++u) {
            int p = w * 2 + u;
            int r = p * 16 + srow;
            gload16(A + (size_t)(bm + r) * K + k0 + schunk * 8, &Al[buf][p * 512]);
            gload16(Bt + (size_t)(bn + r) * K + k0 + schunk * 8, &Bl[buf][p * 512]);
        }
    };

    stage(0, 0);
    const int NT = K / 32;
    const int g = l >> 4;
    for (int tt = 0; tt < NT; ++tt) {
        __syncthreads();
        if (tt + 1 < NT) stage((tt + 1) & 1, (tt + 1) * 32);
        const u16* al = &Al[tt & 1][0];
        const u16* bl = &Bl[tt & 1][0];
        bf16x8 af[4], bf[4];
#pragma unroll
        for (int mb = 0; mb < 4; ++mb) {
            int r = wr * 64 + mb * 16 + (l & 15);
            af[mb] = *(const bf16x8*)(al + r * 32 + ((g ^ (r & 3)) << 3));
            int n = wc * 64 + mb * 16 + (l & 15);
            bf[mb] = *(const bf16x8*)(bl + n * 32 + ((g ^ (n & 3)) << 3));
        }
#pragma unroll
        for (int mb = 0; mb < 4; ++mb)
#pragma unroll
            for (int nb = 0; nb < 4; ++nb)
                acc[mb][nb] = MFMA16(af[mb], bf[nb], acc[mb][nb]);
    }

#pragma unroll
    for (int mb = 0; mb < 4; ++mb) {
        int row = bm + wr * 64 + mb * 16 + (l >> 4) * 4;
#pragma unroll
        for (int nb = 0; nb < 4; ++nb) {
            int col = bn + wc * 64 + nb * 16 + (l & 15);
            float bv = bias[col];
#pragma unroll
            for (int r = 0; r < 4; ++r) {
                float v = acc[mb][nb][r] + bv;
                if (bf16out) ((u16*)Cout)[(size_t)(row + r) * N + col] = f2b(v);
                else        ((float*)Cout)[(size_t)(row + r) * N + col] = v;
            }
        }
    }
}

// ---------------- GEMM bf16 MFMA (64x64 tile): output projection ----------------
// grid (16,64) = 1024 blocks -> 4 blocks/CU. XCD-chunked. No setprio (m190).
__global__ __launch_bounds__(256) void gemm64(
    const u16* __restrict__ A, const u16* __restrict__ Bt,
    const float* __restrict__ bias, float* __restrict__ Cout,
    int M, int N, int K)
{
    __shared__ u16 Al[2][64 * 32];
    __shared__ u16 Bl[2][64 * 32];
    const int t = threadIdx.x, l = t & 63, w = t >> 6;
    const int wr = w >> 1, wc = w & 1;
    const int flat = blockIdx.y * 16 + blockIdx.x;
    const int orig = (flat & 7) * 128 + (flat >> 3);        // 1024 blocks, 128/XCD
    const int bm = (orig >> 4) * 64, bn = (orig & 15) * 64;

    f32x4 acc[2][2];
#pragma unroll
    for (int i = 0; i < 2; ++i)
#pragma unroll
        for (int j = 0; j < 2; ++j) acc[i][j] = (f32x4){0.f, 0.f, 0.f, 0.f};

    const int srow = (l >> 2);
    const int schunk = (l & 3) ^ ((l >> 2) & 3);

    auto stage = [&](int buf, int k0) {
        int r = w * 16 + srow;
        gload16(A + (size_t)(bm + r) * K + k0 + schunk * 8, &Al[buf][w * 512]);
        gload16(Bt + (size_t)(bn + r) * K + k0 + schunk * 8, &Bl[buf][w * 512]);
    };

    stage(0, 0);
    const int NT = K / 32;
    const int g = l >> 4;
    for (int tt = 0; tt < NT; ++tt) {
        __syncthreads();
        if (tt + 1 < NT) stage((tt + 1) & 1, (tt + 1) * 32);
        const u16* al = &Al[tt & 1][0];
        const u16* bl = &Bl[tt & 1][0];
        bf16x8 af[2], bf[2];
#pragma unroll
        for (int mb = 0; mb < 2; ++mb) {
            int r = wr * 32 + mb * 16 + (l & 15);
            af[mb] = *(const bf16x8*)(al + r * 32 + ((g ^ (r & 3)) << 3));
            int n = wc * 32 + mb * 16 + (l & 15);
            bf[mb] = *(const bf16x8*)(bl + n * 32 + ((g ^ (n & 3)) << 3));
        }
#pragma unroll
        for (int mb = 0; mb < 2; ++mb)
#pragma unroll
            for (int nb = 0; nb < 2; ++nb)
                acc[mb][nb] = MFMA16(af[mb], bf[nb], acc[mb][nb]);
    }

#pragma unroll
    for (int mb = 0; mb < 2; ++mb) {
        int row = bm + wr * 32 + mb * 16 + (l >> 4) * 4;
#pragma unroll
        for (int nb = 0; nb < 2; ++nb) {
            int col = bn + wc * 32 + nb * 16 + (l & 15);
            float bv = bias[col];
#pragma unroll
            for (int r = 0; r < 4; ++r)
                Cout[(size_t)(row + r) * N + col] = acc[mb][nb][r] + bv;
        }
    }
}

// ---------------- fused: vectorized RMSNorm q,k (1024 blk) | V transpose (1024 blk) ----------------
__global__ __launch_bounds__(256) void rms_vt(
    const u16* __restrict__ qkvb, const float* __restrict__ gq,
    const float* __restrict__ gk, u16* __restrict__ qb, u16* __restrict__ kb,
    u16* __restrict__ vt)
{
    __shared__ u16 T[64][72];
    const int t = threadIdx.x;
    if (blockIdx.x < 1024) {
        const int row = blockIdx.x * 4 + (t >> 6), lane = t & 63;
        const u16* base = qkvb + (size_t)row * 3072;
        const int d0 = (lane & 7) * 8;
#pragma unroll
        for (int i = 0; i < 4; ++i) {
            int off = i * 512 + lane * 8;
            uint4 xv = *(const uint4*)(base + off);
            const u16* e = (const u16*)&xv;
            float f[8]; float ss = 0.f;
#pragma unroll
            for (int j = 0; j < 8; ++j) { f[j] = b2f(e[j]); ss += f[j] * f[j]; }
            ss += __shfl_xor(ss, 1, 64);
            ss += __shfl_xor(ss, 2, 64);
            ss += __shfl_xor(ss, 4, 64);
            float inv = rsqrtf(fmaxf(ss, 1e-24f));
            int vec = i * 8 + (lane >> 3);
            int isK = vec >> 4, h = vec & 15;
            const float* gm = (isK ? gk : gq) + h * 64 + d0;
            float4 g0 = *(const float4*)gm;
            float4 g1 = *(const float4*)(gm + 4);
            float gg[8] = { g0.x, g0.y, g0.z, g0.w, g1.x, g1.y, g1.z, g1.w };
            float scale = isK ? 8.0f : LOG2E;
            u16 ov[8];
#pragma unroll
            for (int j = 0; j < 8; ++j) ov[j] = f2b(f[j] * inv * gg[j] * scale);
            u16* dst = (isK ? kb : qb) + (size_t)row * 1024 + h * 64 + d0;
            *(uint4*)dst = *(uint4*)ov;
        }
        return;
    }
    const int blk = blockIdx.x - 1024;
    const int nt = blk & 31;
    const int bh = blk >> 5;
    const int b = bh >> 4, h = bh & 15;
#pragma unroll
    for (int u = 0; u < 2; ++u) {
        int f = t + u * 256;
        int n = f >> 3, c = f & 7;
        uint4 v = *(const uint4*)(qkvb + (size_t)(b * 2048 + nt * 64 + n) * 3072 + 2048 + h * 64 + c * 8);
        *(uint4*)&T[n][c * 8] = v;
    }
    __syncthreads();
    int d = t >> 2;
    u16 tmp[16];
#pragma unroll
    for (int i = 0; i < 16; ++i) tmp[i] = T[(t & 3) * 16 + i][d];
    u16* o = vt + ((size_t)bh * 64 + d) * 2048 + nt * 64 + (t & 3) * 16;
    *(uint4*)o       = *(uint4*)&tmp[0];
    *(uint4*)(o + 8) = *(uint4*)&tmp[8];
}

// ---------------- Flash attention, KV-split x4, fixed max, double-buffer (r13 config) ----------------
// (256,4): the measured occupancy knee — 60 VGPR, no spill. No setprio (lockstep structure).
__global__ __launch_bounds__(256, 4) void attn_mfma(
    const u16* __restrict__ qb, const u16* __restrict__ kbuf,
    const u16* __restrict__ vt, u16* __restrict__ op012, u16* __restrict__ op3,
    float* __restrict__ lsums)
{
    __shared__ u16 Kl[2][4096];
    __shared__ u16 Vl[2][4096];

    const int t = threadIdx.x, l = t & 63, w = t >> 6;
    const int hi = l >> 5, lq = l & 31;
    const int orig = ((blockIdx.x & 7) << 8) | (blockIdx.x >> 3);   // XCD-chunked
    const int qt = orig & 15;
    const int s  = (orig >> 4) & 3;        // KV split 0..3 (512 rows each)
    const int bh = orig >> 6;
    const int b = bh >> 4, h = bh & 15;
    const int bq = bh * 16 + qt;
    const int kv0 = s * 512;

    const int qrow = b * 2048 + qt * 128 + w * 32 + lq;
    bf16x8 qf[4];
#pragma unroll
    for (int ds = 0; ds < 4; ++ds)
        qf[ds] = *(const bf16x8*)(qb + (size_t)qrow * 1024 + h * 64 + ds * 16 + hi * 8);

    f32x16 O0, O1;
#pragma unroll
    for (int r = 0; r < 16; ++r) { O0[r] = 0.f; O1[r] = 0.f; }
    float lsum = 0.f;

    auto stage = [&](int buf, int kt) {
#pragma unroll
        for (int u = 0; u < 2; ++u) {
            int p = w * 2 + u;
            int row = p * 8 + (l >> 3);          // LDS slot row
            int c = (l & 7) ^ (row & 7);         // pre-swizzled source chunk
            int r5 = row & 31;
            int bb = (r5 >> 2) & 3;
            int grow = (row & 32) | ((bb == 1 || bb == 2) ? (r5 ^ 12) : r5);
            gload16(kbuf + (size_t)(b * 2048 + kv0 + kt * 64 + grow) * 1024 + h * 64 + c * 8,
                    &Kl[buf][p * 512]);
            gload16(vt + ((size_t)bh * 64 + row) * 2048 + kv0 + kt * 64 + c * 8,
                    &Vl[buf][p * 512]);
        }
    };

    stage(0, 0);
    for (int kt = 0; kt < 8; ++kt) {
        __syncthreads();                        // drains stage(kt); frees buf[(kt+1)&1]
        if (kt + 1 < 8) stage((kt + 1) & 1, kt + 1);   // overlaps compute
        const u16* kl = &Kl[kt & 1][0];
        const u16* vl = &Vl[kt & 1][0];

        // S^T = K.Q^T (rows = pi-permuted k, cols = q on lane&31)
        f32x16 S0, S1;
#pragma unroll
        for (int r = 0; r < 16; ++r) { S0[r] = 0.f; S1[r] = 0.f; }
#pragma unroll
        for (int ds = 0; ds < 4; ++ds) {
            int ch = ds * 2 + hi;
            int r0 = lq, r1 = lq + 32;
            bf16x8 kf0 = *(const bf16x8*)(kl + r0 * 64 + ((ch ^ (r0 & 7)) << 3));
            bf16x8 kf1 = *(const bf16x8*)(kl + r1 * 64 + ((ch ^ (r1 & 7)) << 3));
            S0 = MFMA32(kf0, qf[ds], S0);
            S1 = MFMA32(kf1, qf[ds], S1);
        }

        // P = 2^(S - 12), fixed max (Cauchy-Schwarz bound, RMS-normed q,k)
#pragma unroll
        for (int r = 0; r < 16; ++r) {
            S0[r] = exp2_raw(S0[r] - 12.0f);
            S1[r] = exp2_raw(S1[r] - 12.0f);
        }
        float sp[16];
#pragma unroll
        for (int r = 0; r < 16; ++r) sp[r] = S0[r] + S1[r];
#pragma unroll
        for (int s2 = 8; s2 > 0; s2 >>= 1)
#pragma unroll
            for (int r = 0; r < 8; ++r)
                if (r < s2) sp[r] += sp[r + s2];
        lsum += sp[0];

        // pack P: pi-permutation -> straight cvt_pk of registers
        bf16x8 pa[4];
        {
            unsigned x0[8], x1[8];
#pragma unroll
            for (int i = 0; i < 8; ++i) {
                asm("v_cvt_pk_bf16_f32 %0, %1, %2"
                    : "=v"(x0[i]) : "v"(S0[2 * i]), "v"(S0[2 * i + 1]));
                asm("v_cvt_pk_bf16_f32 %0, %1, %2"
                    : "=v"(x1[i]) : "v"(S1[2 * i]), "v"(S1[2 * i + 1]));
            }
            union { unsigned wv[4]; bf16x8 v; } uu;
            uu.wv[0] = x0[0]; uu.wv[1] = x0[1]; uu.wv[2] = x0[2]; uu.wv[3] = x0[3];
            pa[0] = uu.v;
            uu.wv[0] = x0[4]; uu.wv[1] = x0[5]; uu.wv[2] = x0[6]; uu.wv[3] = x0[7];
            pa[1] = uu.v;
            uu.wv[0] = x1[0]; uu.wv[1] = x1[1]; uu.wv[2] = x1[2]; uu.wv[3] = x1[3];
            pa[2] = uu.v;
            uu.wv[0] = x1[4]; uu.wv[1] = x1[5]; uu.wv[2] = x1[6]; uu.wv[3] = x1[7];
            pa[3] = uu.v;
        }

        // O^T += V^T @ P^T
#pragma unroll
        for (int ks = 0; ks < 4; ++ks) {
            int ch = ks * 2 + hi;
            int r0 = lq, r1 = lq + 32;
            bf16x8 vf0 = *(const bf16x8*)(vl + r0 * 64 + ((ch ^ (r0 & 7)) << 3));
            bf16x8 vf1 = *(const bf16x8*)(vl + r1 * 64 + ((ch ^ (r1 & 7)) << 3));
            O0 = MFMA32(vf0, pa[ks], O0);
            O1 = MFMA32(vf1, pa[ks], O1);
        }
    }

    // epilogue: unnormalized partial O (bf16) + lsum (f32, one lane per q-row)
    u16* ob = ((s == 3) ? op3 : op012 + (size_t)s * 4194304)
              + ((size_t)bq * 128 + (w * 32 + lq)) * 64;
    f32x16 Ox[2] = { O0, O1 };
#pragma unroll
    for (int db = 0; db < 2; ++db) {
#pragma unroll
        for (int a = 0; a < 4; ++a) {
            int d0 = a * 8 + hi * 4 + db * 32;
            unsigned long long pk = 0;
#pragma unroll
            for (int bb = 0; bb < 4; ++bb)
                pk |= (unsigned long long)f2b(Ox[db][a * 4 + bb]) << (16 * bb);
            *(unsigned long long*)(ob + d0) = pk;
        }
    }
    float ltot = lsum + __shfl_xor(lsum, 32, 64);
    if (hi == 0)
        lsums[((size_t)s * 512 + bq) * 128 + w * 32 + lq] = ltot;
}

// ---------------- combine the 4 KV-splits (shared m -> plain weighted sum) ----------------
__global__ __launch_bounds__(256) void attn_combine(
    const u16* __restrict__ op012, const u16* __restrict__ op3,
    const float* __restrict__ lsums, u16* __restrict__ attnb)
{
    const int t = threadIdx.x;
    const int bq = blockIdx.x >> 1, qh = blockIdx.x & 1;
    const int bh = bq >> 4, qt = bq & 15;
    const int b = bh >> 4, h = bh & 15;
    const int q = qh * 64 + (t >> 2), dseg = (t & 3) * 16;

    float l = 0.f;
#pragma unroll
    for (int sp = 0; sp < 4; ++sp)
        l += lsums[((size_t)sp * 512 + bq) * 128 + q];
    float linv = 1.0f / l;

    float acc[16];
#pragma unroll
    for (int e = 0; e < 16; ++e) acc[e] = 0.f;
#pragma unroll
    for (int sp = 0; sp < 4; ++sp) {
        const u16* p = ((sp == 3) ? op3 : op012 + (size_t)sp * 4194304)
                       + ((size_t)bq * 128 + q) * 64 + dseg;
        uint4 x0 = *(const uint4*)p;
        uint4 x1 = *(const uint4*)(p + 8);
        const u16* e0 = (const u16*)&x0;
        const u16* e1 = (const u16*)&x1;
#pragma unroll
        for (int e = 0; e < 8; ++e) { acc[e] += b2f(e0[e]); acc[8 + e] += b2f(e1[e]); }
    }
    u16 ov[16];
#pragma unroll
    for (int e = 0; e < 16; ++e) ov[e] = f2b(acc[e] * linv);
    u16* o = attnb + (size_t)(b * 2048 + qt * 128 + q) * 1024 + h * 64 + dseg;
    *(uint4*)o       = *(uint4*)&ov[0];
    *(uint4*)(o + 8) = *(uint4*)&ov[8];
}

extern "C" void kernel_launch(void* const* d_in, const int* in_sizes, int n_in,
                              void* d_out, int out_size, void* d_ws, size_t ws_size,
                              hipStream_t stream)
{
    const float* x    = (const float*)d_in[0];
    const float* Wqkv = (const float*)d_in[1];
    const float* bqkv = (const float*)d_in[2];
    const float* gq   = (const float*)d_in[3];
    const float* gk   = (const float*)d_in[4];
    const float* Wout = (const float*)d_in[5];
    const float* bout = (const float*)d_in[6];
    float* out = (float*)d_out;

    char* ws = (char*)d_ws;
    u16* xb     = (u16*)(ws);                 // prep -> gemm1
    u16* op3    = (u16*)(ws);                 // attn -> combine   (xb dead)
    u16* wqkvt  = (u16*)(ws + ( 8u << 20));   // prep -> gemm1
    float* lsums= (float*)(ws + ( 8u << 20)); // attn -> combine   (wqkvt dead)
    u16* woutt  = (u16*)(ws + (14u << 20));   // prep -> gemm2
    u16* qkvb   = (u16*)(ws + (16u << 20));   // gemm1 -> rms_vt
    u16* op012  = (u16*)(ws + (16u << 20));   // attn -> combine   (qkvb dead)
    u16* qbuf   = (u16*)(ws + (40u << 20));   // rms_vt -> attn
    u16* attnb  = (u16*)(ws + (40u << 20));   // combine -> gemm2  (qbuf dead)
    u16* kbuf   = (u16*)(ws + (48u << 20));   // rms_vt -> attn
    u16* vtb    = (u16*)(ws + (56u << 20));   // rms_vt -> attn

    prep<<<3072, 256, 0, stream>>>(x, Wqkv, Wout, xb, wqkvt, woutt);
    gemm_bf16<<<dim3(24, 32), 256, 0, stream>>>(xb, wqkvt, bqkv, qkvb, M_, 3072, 1024, 1);
    rms_vt<<<2048, 256, 0, stream>>>(qkvb, gq, gk, qbuf, kbuf, vtb);
    attn_mfma<<<2048, 256, 0, stream>>>(qbuf, kbuf, vtb, op012, op3, lsums);
    attn_combine<<<1024, 256, 0, stream>>>(op012, op3, lsums, attnb);
    gemm64<<<dim3(16, 64), 256, 0, stream>>>(attnb, woutt, bout, out, M_, 1024, 1024);
}

// Round 19
// 127.299 us; speedup vs baseline: 1.1481x; 1.0052x over previous
//
#include <hip/hip_runtime.h>

#define B_ 2
#define N_ 2048
#define C_ 1024
#define H_ 16
#define D_ 64
#define M_ (B_*N_)   // 4096
#define LOG2E 1.44269504088896340736f

typedef __bf16 bf16x8 __attribute__((ext_vector_type(8)));
typedef float  f32x4  __attribute__((ext_vector_type(4)));
typedef float  f32x16 __attribute__((ext_vector_type(16)));
typedef unsigned short u16;

#define MFMA16(a, b, c) __builtin_amdgcn_mfma_f32_16x16x32_bf16(a, b, c, 0, 0, 0)
#define MFMA32(a, b, c) __builtin_amdgcn_mfma_f32_32x32x16_bf16(a, b, c, 0, 0, 0)

__device__ __forceinline__ u16 f2b(float f) {
    union { float f; unsigned int u; } v; v.f = f;
    unsigned int r = (v.u + 0x7fffu + ((v.u >> 16) & 1u)) >> 16;
    return (u16)r;
}
__device__ __forceinline__ float b2f(u16 h) {
    union { unsigned int u; float f; } v; v.u = ((unsigned int)h) << 16;
    return v.f;
}
// raw 2^x — args bounded in [-35, 0]: no denorm fixup needed (libm exp2f adds ~4 ops)
__device__ __forceinline__ float exp2_raw(float x) {
    float r;
    asm("v_exp_f32 %0, %1" : "=v"(r) : "v"(x));
    return r;
}
__device__ __forceinline__ void gload16(const void* g, void* lds) {
    __builtin_amdgcn_global_load_lds(
        (const __attribute__((address_space(1))) unsigned int*)g,
        (__attribute__((address_space(3))) unsigned int*)lds, 16, 0, 0);
}

// ---------------- fused prep: x->bf16 (2048 blk) | WqkvT (768) | WoutT (256) ----------------
__global__ __launch_bounds__(256) void prep(
    const float* __restrict__ x, const float* __restrict__ Wqkv,
    const float* __restrict__ Wout, u16* __restrict__ xb,
    u16* __restrict__ wqkvt, u16* __restrict__ woutt)
{
    __shared__ u16 T[64][72];
    const int t = threadIdx.x;
    const int bid = blockIdx.x;
    if (bid < 2048) {
        int i = bid * 256 + t;
        float4 a = *(const float4*)(x + (size_t)i * 8);
        float4 b = *(const float4*)(x + (size_t)i * 8 + 4);
        u16 tmp[8] = { f2b(a.x), f2b(a.y), f2b(a.z), f2b(a.w),
                       f2b(b.x), f2b(b.y), f2b(b.z), f2b(b.w) };
        *(uint4*)(xb + (size_t)i * 8) = *(uint4*)tmp;
        return;
    }
    const float* W; u16* Wt; int K, N, blk;
    if (bid < 2048 + 768) { W = Wqkv; Wt = wqkvt; K = 1024; N = 3072; blk = bid - 2048; }
    else                  { W = Wout; Wt = woutt; K = 1024; N = 1024; blk = bid - 2816; }
    const int ntiles = N >> 6;
    const int kt = blk / ntiles, ntl = blk % ntiles;
#pragma unroll
    for (int u = 0; u < 2; ++u) {
        int f = t + u * 256;
        int r = f >> 3, c = f & 7;
        const float* p = W + (size_t)(kt * 64 + r) * N + ntl * 64 + c * 8;
        float4 a = *(const float4*)p;
        float4 b = *(const float4*)(p + 4);
        u16 tmp[8] = { f2b(a.x), f2b(a.y), f2b(a.z), f2b(a.w),
                       f2b(b.x), f2b(b.y), f2b(b.z), f2b(b.w) };
        *(uint4*)&T[r][c * 8] = *(uint4*)tmp;
    }
    __syncthreads();
    int n = t >> 2;
    u16 tmp[16];
#pragma unroll
    for (int i = 0; i < 16; ++i) tmp[i] = T[(t & 3) * 16 + i][n];
    u16* o = Wt + (size_t)(ntl * 64 + n) * K + kt * 64 + (t & 3) * 16;
    *(uint4*)o       = *(uint4*)&tmp[0];
    *(uint4*)(o + 8) = *(uint4*)&tmp[8];
}

// ---------------- GEMM bf16 MFMA (128x128 tile): qkv projection ----------------
// grid (24,32); XCD-chunked swizzle: each XCD owns 4 contiguous bm rows (A-panel L2 reuse)
__global__ __launch_bounds__(256) void gemm_bf16(
    const u16* __restrict__ A, const u16* __restrict__ Bt,
    const float* __restrict__ bias, void* __restrict__ Cout,
    int M, int N, int K, int bf16out)
{
    __shared__ u16 Al[2][128 * 32];
    __shared__ u16 Bl[2][128 * 32];
    const int t = threadIdx.x, l = t & 63, w = t >> 6;
    const int wr = w >> 1, wc = w & 1;
    const int flat = blockIdx.y * 24 + blockIdx.x;          // dispatch order (x fastest)
    const int orig = (flat & 7) * 96 + (flat >> 3);         // 768 blocks, 96/XCD
    const int bm = (orig / 24) * 128, bn = (orig % 24) * 128;

    f32x4 acc[4][4];
#pragma unroll
    for (int i = 0; i < 4; ++i)
#pragma unroll
        for (int j = 0; j < 4; ++j) acc[i][j] = (f32x4){0.f, 0.f, 0.f, 0.f};

    const int srow = (l >> 2);
    const int schunk = (l & 3) ^ ((l >> 2) & 3);

    auto stage = [&](int buf, int k0) {
#pragma unroll
        for (int u = 0; u < 2; ++u) {
            int p = w * 2 + u;
            int r = p * 16 + srow;
            gload16(A + (size_t)(bm + r) * K + k0 + schunk * 8, &Al[buf][p * 512]);
            gload16(Bt + (size_t)(bn + r) * K + k0 + schunk * 8, &Bl[buf][p * 512]);
        }
    };

    stage(0, 0);
    const int NT = K / 32;
    const int g = l >> 4;
    for (int tt = 0; tt < NT; ++tt) {
        __syncthreads();
        if (tt + 1 < NT) stage((tt + 1) & 1, (tt + 1) * 32);
        const u16* al = &Al[tt & 1][0];
        const u16* bl = &Bl[tt & 1][0];
        bf16x8 af[4], bf[4];
#pragma unroll
        for (int mb = 0; mb < 4; ++mb) {
            int r = wr * 64 + mb * 16 + (l & 15);
            af[mb] = *(const bf16x8*)(al + r * 32 + ((g ^ (r & 3)) << 3));
            int n = wc * 64 + mb * 16 + (l & 15);
            bf[mb] = *(const bf16x8*)(bl + n * 32 + ((g ^ (n & 3)) << 3));
        }
        __builtin_amdgcn_s_setprio(1);
#pragma unroll
        for (int mb = 0; mb < 4; ++mb)
#pragma unroll
            for (int nb = 0; nb < 4; ++nb)
                acc[mb][nb] = MFMA16(af[mb], bf[nb], acc[mb][nb]);
        __builtin_amdgcn_s_setprio(0);
    }

#pragma unroll
    for (int mb = 0; mb < 4; ++mb) {
        int row = bm + wr * 64 + mb * 16 + (l >> 4) * 4;
#pragma unroll
        for (int nb = 0; nb < 4; ++nb) {
            int col = bn + wc * 64 + nb * 16 + (l & 15);
            float bv = bias[col];
#pragma unroll
            for (int r = 0; r < 4; ++r) {
                float v = acc[mb][nb][r] + bv;
                if (bf16out) ((u16*)Cout)[(size_t)(row + r) * N + col] = f2b(v);
                else        ((float*)Cout)[(size_t)(row + r) * N + col] = v;
            }
        }
    }
}

// ---------------- GEMM bf16 MFMA (64x64 tile): output projection ----------------
// grid (16,64) = 1024 blocks -> 4 blocks/CU. XCD-chunked: 8 bm rows per XCD.
__global__ __launch_bounds__(256) void gemm64(
    const u16* __restrict__ A, const u16* __restrict__ Bt,
    const float* __restrict__ bias, float* __restrict__ Cout,
    int M, int N, int K)
{
    __shared__ u16 Al[2][64 * 32];
    __shared__ u16 Bl[2][64 * 32];
    const int t = threadIdx.x, l = t & 63, w = t >> 6;
    const int wr = w >> 1, wc = w & 1;
    const int flat = blockIdx.y * 16 + blockIdx.x;
    const int orig = (flat & 7) * 128 + (flat >> 3);        // 1024 blocks, 128/XCD
    const int bm = (orig >> 4) * 64, bn = (orig & 15) * 64;

    f32x4 acc[2][2];
#pragma unroll
    for (int i = 0; i < 2; ++i)
#pragma unroll
        for (int j = 0; j < 2; ++j) acc[i][j] = (f32x4){0.f, 0.f, 0.f, 0.f};

    const int srow = (l >> 2);
    const int schunk = (l & 3) ^ ((l >> 2) & 3);

    auto stage = [&](int buf, int k0) {
        int r = w * 16 + srow;
        gload16(A + (size_t)(bm + r) * K + k0 + schunk * 8, &Al[buf][w * 512]);
        gload16(Bt + (size_t)(bn + r) * K + k0 + schunk * 8, &Bl[buf][w * 512]);
    };

    stage(0, 0);
    const int NT = K / 32;
    const int g = l >> 4;
    for (int tt = 0; tt < NT; ++tt) {
        __syncthreads();
        if (tt + 1 < NT) stage((tt + 1) & 1, (tt + 1) * 32);
        const u16* al = &Al[tt & 1][0];
        const u16* bl = &Bl[tt & 1][0];
        bf16x8 af[2], bf[2];
#pragma unroll
        for (int mb = 0; mb < 2; ++mb) {
            int r = wr * 32 + mb * 16 + (l & 15);
            af[mb] = *(const bf16x8*)(al + r * 32 + ((g ^ (r & 3)) << 3));
            int n = wc * 32 + mb * 16 + (l & 15);
            bf[mb] = *(const bf16x8*)(bl + n * 32 + ((g ^ (n & 3)) << 3));
        }
        __builtin_amdgcn_s_setprio(1);
#pragma unroll
        for (int mb = 0; mb < 2; ++mb)
#pragma unroll
            for (int nb = 0; nb < 2; ++nb)
                acc[mb][nb] = MFMA16(af[mb], bf[nb], acc[mb][nb]);
        __builtin_amdgcn_s_setprio(0);
    }

#pragma unroll
    for (int mb = 0; mb < 2; ++mb) {
        int row = bm + wr * 32 + mb * 16 + (l >> 4) * 4;
#pragma unroll
        for (int nb = 0; nb < 2; ++nb) {
            int col = bn + wc * 32 + nb * 16 + (l & 15);
            float bv = bias[col];
#pragma unroll
            for (int r = 0; r < 4; ++r)
                Cout[(size_t)(row + r) * N + col] = acc[mb][nb][r] + bv;
        }
    }
}

// ---------------- fused: vectorized RMSNorm q,k (1024 blk) | V transpose (1024 blk) ----------------
__global__ __launch_bounds__(256) void rms_vt(
    const u16* __restrict__ qkvb, const float* __restrict__ gq,
    const float* __restrict__ gk, u16* __restrict__ qb, u16* __restrict__ kb,
    u16* __restrict__ vt)
{
    __shared__ u16 T[64][72];
    const int t = threadIdx.x;
    if (blockIdx.x < 1024) {
        const int row = blockIdx.x * 4 + (t >> 6), lane = t & 63;
        const u16* base = qkvb + (size_t)row * 3072;
        const int d0 = (lane & 7) * 8;
#pragma unroll
        for (int i = 0; i < 4; ++i) {
            int off = i * 512 + lane * 8;
            uint4 xv = *(const uint4*)(base + off);
            const u16* e = (const u16*)&xv;
            float f[8]; float ss = 0.f;
#pragma unroll
            for (int j = 0; j < 8; ++j) { f[j] = b2f(e[j]); ss += f[j] * f[j]; }
            ss += __shfl_xor(ss, 1, 64);
            ss += __shfl_xor(ss, 2, 64);
            ss += __shfl_xor(ss, 4, 64);
            float inv = rsqrtf(fmaxf(ss, 1e-24f));
            int vec = i * 8 + (lane >> 3);
            int isK = vec >> 4, h = vec & 15;
            const float* gm = (isK ? gk : gq) + h * 64 + d0;
            float4 g0 = *(const float4*)gm;
            float4 g1 = *(const float4*)(gm + 4);
            float gg[8] = { g0.x, g0.y, g0.z, g0.w, g1.x, g1.y, g1.z, g1.w };
            float scale = isK ? 8.0f : LOG2E;
            u16 ov[8];
#pragma unroll
            for (int j = 0; j < 8; ++j) ov[j] = f2b(f[j] * inv * gg[j] * scale);
            u16* dst = (isK ? kb : qb) + (size_t)row * 1024 + h * 64 + d0;
            *(uint4*)dst = *(uint4*)ov;
        }
        return;
    }
    const int blk = blockIdx.x - 1024;
    const int nt = blk & 31;
    const int bh = blk >> 5;
    const int b = bh >> 4, h = bh & 15;
#pragma unroll
    for (int u = 0; u < 2; ++u) {
        int f = t + u * 256;
        int n = f >> 3, c = f & 7;
        uint4 v = *(const uint4*)(qkvb + (size_t)(b * 2048 + nt * 64 + n) * 3072 + 2048 + h * 64 + c * 8);
        *(uint4*)&T[n][c * 8] = v;
    }
    __syncthreads();
    int d = t >> 2;
    u16 tmp[16];
#pragma unroll
    for (int i = 0; i < 16; ++i) tmp[i] = T[(t & 3) * 16 + i][d];
    u16* o = vt + ((size_t)bh * 64 + d) * 2048 + nt * 64 + (t & 3) * 16;
    *(uint4*)o       = *(uint4*)&tmp[0];
    *(uint4*)(o + 8) = *(uint4*)&tmp[8];
}

// ---------------- Flash attention, KV-split x4, fixed max, double-buffer (r13 config) ----------------
// (256,4): the measured occupancy knee — 60 VGPR, no spill. (256,5) forces VGPR cap 48
// -> 103MB scratch (r12); (256,8) -> 32 VGPR, 1.3GB scratch (r7); free -> 96 VGPR, 20% occ (r8).
__global__ __launch_bounds__(256, 4) void attn_mfma(
    const u16* __restrict__ qb, const u16* __restrict__ kbuf,
    const u16* __restrict__ vt, u16* __restrict__ op012, u16* __restrict__ op3,
    float* __restrict__ lsums)
{
    __shared__ u16 Kl[2][4096];
    __shared__ u16 Vl[2][4096];

    const int t = threadIdx.x, l = t & 63, w = t >> 6;
    const int hi = l >> 5, lq = l & 31;
    const int orig = ((blockIdx.x & 7) << 8) | (blockIdx.x >> 3);   // XCD-chunked
    const int qt = orig & 15;
    const int s  = (orig >> 4) & 3;        // KV split 0..3 (512 rows each)
    const int bh = orig >> 6;
    const int b = bh >> 4, h = bh & 15;
    const int bq = bh * 16 + qt;
    const int kv0 = s * 512;

    const int qrow = b * 2048 + qt * 128 + w * 32 + lq;
    bf16x8 qf[4];
#pragma unroll
    for (int ds = 0; ds < 4; ++ds)
        qf[ds] = *(const bf16x8*)(qb + (size_t)qrow * 1024 + h * 64 + ds * 16 + hi * 8);

    f32x16 O0, O1;
#pragma unroll
    for (int r = 0; r < 16; ++r) { O0[r] = 0.f; O1[r] = 0.f; }
    float lsum = 0.f;

    auto stage = [&](int buf, int kt) {
#pragma unroll
        for (int u = 0; u < 2; ++u) {
            int p = w * 2 + u;
            int row = p * 8 + (l >> 3);          // LDS slot row
            int c = (l & 7) ^ (row & 7);         // pre-swizzled source chunk
            int r5 = row & 31;
            int bb = (r5 >> 2) & 3;
            int grow = (row & 32) | ((bb == 1 || bb == 2) ? (r5 ^ 12) : r5);
            gload16(kbuf + (size_t)(b * 2048 + kv0 + kt * 64 + grow) * 1024 + h * 64 + c * 8,
                    &Kl[buf][p * 512]);
            gload16(vt + ((size_t)bh * 64 + row) * 2048 + kv0 + kt * 64 + c * 8,
                    &Vl[buf][p * 512]);
        }
    };

    stage(0, 0);
    for (int kt = 0; kt < 8; ++kt) {
        __syncthreads();                        // drains stage(kt); frees buf[(kt+1)&1]
        if (kt + 1 < 8) stage((kt + 1) & 1, kt + 1);   // overlaps compute
        const u16* kl = &Kl[kt & 1][0];
        const u16* vl = &Vl[kt & 1][0];

        // S^T = K.Q^T (rows = pi-permuted k, cols = q on lane&31)
        f32x16 S0, S1;
#pragma unroll
        for (int r = 0; r < 16; ++r) { S0[r] = 0.f; S1[r] = 0.f; }
        __builtin_amdgcn_s_setprio(1);
#pragma unroll
        for (int ds = 0; ds < 4; ++ds) {
            int ch = ds * 2 + hi;
            int r0 = lq, r1 = lq + 32;
            bf16x8 kf0 = *(const bf16x8*)(kl + r0 * 64 + ((ch ^ (r0 & 7)) << 3));
            bf16x8 kf1 = *(const bf16x8*)(kl + r1 * 64 + ((ch ^ (r1 & 7)) << 3));
            S0 = MFMA32(kf0, qf[ds], S0);
            S1 = MFMA32(kf1, qf[ds], S1);
        }
        __builtin_amdgcn_s_setprio(0);

        // P = 2^(S - 12), fixed max (Cauchy-Schwarz bound, RMS-normed q,k)
#pragma unroll
        for (int r = 0; r < 16; ++r) {
            S0[r] = exp2_raw(S0[r] - 12.0f);
            S1[r] = exp2_raw(S1[r] - 12.0f);
        }
        float sp[16];
#pragma unroll
        for (int r = 0; r < 16; ++r) sp[r] = S0[r] + S1[r];
#pragma unroll
        for (int s2 = 8; s2 > 0; s2 >>= 1)
#pragma unroll
            for (int r = 0; r < 8; ++r)
                if (r < s2) sp[r] += sp[r + s2];
        lsum += sp[0];

        // pack P: pi-permutation -> straight cvt_pk of registers
        bf16x8 pa[4];
        {
            unsigned x0[8], x1[8];
#pragma unroll
            for (int i = 0; i < 8; ++i) {
                asm("v_cvt_pk_bf16_f32 %0, %1, %2"
                    : "=v"(x0[i]) : "v"(S0[2 * i]), "v"(S0[2 * i + 1]));
                asm("v_cvt_pk_bf16_f32 %0, %1, %2"
                    : "=v"(x1[i]) : "v"(S1[2 * i]), "v"(S1[2 * i + 1]));
            }
            union { unsigned wv[4]; bf16x8 v; } uu;
            uu.wv[0] = x0[0]; uu.wv[1] = x0[1]; uu.wv[2] = x0[2]; uu.wv[3] = x0[3];
            pa[0] = uu.v;
            uu.wv[0] = x0[4]; uu.wv[1] = x0[5]; uu.wv[2] = x0[6]; uu.wv[3] = x0[7];
            pa[1] = uu.v;
            uu.wv[0] = x1[0]; uu.wv[1] = x1[1]; uu.wv[2] = x1[2]; uu.wv[3] = x1[3];
            pa[2] = uu.v;
            uu.wv[0] = x1[4]; uu.wv[1] = x1[5]; uu.wv[2] = x1[6]; uu.wv[3] = x1[7];
            pa[3] = uu.v;
        }

        // O^T += V^T @ P^T
        __builtin_amdgcn_s_setprio(1);
#pragma unroll
        for (int ks = 0; ks < 4; ++ks) {
            int ch = ks * 2 + hi;
            int r0 = lq, r1 = lq + 32;
            bf16x8 vf0 = *(const bf16x8*)(vl + r0 * 64 + ((ch ^ (r0 & 7)) << 3));
            bf16x8 vf1 = *(const bf16x8*)(vl + r1 * 64 + ((ch ^ (r1 & 7)) << 3));
            O0 = MFMA32(vf0, pa[ks], O0);
            O1 = MFMA32(vf1, pa[ks], O1);
        }
        __builtin_amdgcn_s_setprio(0);
    }

    // epilogue: unnormalized partial O (bf16) + lsum (f32, one lane per q-row)
    u16* ob = ((s == 3) ? op3 : op012 + (size_t)s * 4194304)
              + ((size_t)bq * 128 + (w * 32 + lq)) * 64;
    f32x16 Ox[2] = { O0, O1 };
#pragma unroll
    for (int db = 0; db < 2; ++db) {
#pragma unroll
        for (int a = 0; a < 4; ++a) {
            int d0 = a * 8 + hi * 4 + db * 32;
            unsigned long long pk = 0;
#pragma unroll
            for (int bb = 0; bb < 4; ++bb)
                pk |= (unsigned long long)f2b(Ox[db][a * 4 + bb]) << (16 * bb);
            *(unsigned long long*)(ob + d0) = pk;
        }
    }
    float ltot = lsum + __shfl_xor(lsum, 32, 64);
    if (hi == 0)
        lsums[((size_t)s * 512 + bq) * 128 + w * 32 + lq] = ltot;
}

// ---------------- combine the 4 KV-splits (shared m -> plain weighted sum) ----------------
__global__ __launch_bounds__(256) void attn_combine(
    const u16* __restrict__ op012, const u16* __restrict__ op3,
    const float* __restrict__ lsums, u16* __restrict__ attnb)
{
    const int t = threadIdx.x;
    const int bq = blockIdx.x >> 1, qh = blockIdx.x & 1;
    const int bh = bq >> 4, qt = bq & 15;
    const int b = bh >> 4, h = bh & 15;
    const int q = qh * 64 + (t >> 2), dseg = (t & 3) * 16;

    float l = 0.f;
#pragma unroll
    for (int sp = 0; sp < 4; ++sp)
        l += lsums[((size_t)sp * 512 + bq) * 128 + q];
    float linv = 1.0f / l;

    float acc[16];
#pragma unroll
    for (int e = 0; e < 16; ++e) acc[e] = 0.f;
#pragma unroll
    for (int sp = 0; sp < 4; ++sp) {
        const u16* p = ((sp == 3) ? op3 : op012 + (size_t)sp * 4194304)
                       + ((size_t)bq * 128 + q) * 64 + dseg;
        uint4 x0 = *(const uint4*)p;
        uint4 x1 = *(const uint4*)(p + 8);
        const u16* e0 = (const u16*)&x0;
        const u16* e1 = (const u16*)&x1;
#pragma unroll
        for (int e = 0; e < 8; ++e) { acc[e] += b2f(e0[e]); acc[8 + e] += b2f(e1[e]); }
    }
    u16 ov[16];
#pragma unroll
    for (int e = 0; e < 16; ++e) ov[e] = f2b(acc[e] * linv);
    u16* o = attnb + (size_t)(b * 2048 + qt * 128 + q) * 1024 + h * 64 + dseg;
    *(uint4*)o       = *(uint4*)&ov[0];
    *(uint4*)(o + 8) = *(uint4*)&ov[8];
}

extern "C" void kernel_launch(void* const* d_in, const int* in_sizes, int n_in,
                              void* d_out, int out_size, void* d_ws, size_t ws_size,
                              hipStream_t stream)
{
    const float* x    = (const float*)d_in[0];
    const float* Wqkv = (const float*)d_in[1];
    const float* bqkv = (const float*)d_in[2];
    const float* gq   = (const float*)d_in[3];
    const float* gk   = (const float*)d_in[4];
    const float* Wout = (const float*)d_in[5];
    const float* bout = (const float*)d_in[6];
    float* out = (float*)d_out;

    char* ws = (char*)d_ws;
    u16* xb     = (u16*)(ws);                 // prep -> gemm1
    u16* op3    = (u16*)(ws);                 // attn -> combine   (xb dead)
    u16* wqkvt  = (u16*)(ws + ( 8u << 20));   // prep -> gemm1
    float* lsums= (float*)(ws + ( 8u << 20)); // attn -> combine   (wqkvt dead)
    u16* woutt  = (u16*)(ws + (14u << 20));   // prep -> gemm2
    u16* qkvb   = (u16*)(ws + (16u << 20));   // gemm1 -> rms_vt
    u16* op012  = (u16*)(ws + (16u << 20));   // attn -> combine   (qkvb dead)
    u16* qbuf   = (u16*)(ws + (40u << 20));   // rms_vt -> attn
    u16* attnb  = (u16*)(ws + (40u << 20));   // combine -> gemm2  (qbuf dead)
    u16* kbuf   = (u16*)(ws + (48u << 20));   // rms_vt -> attn
    u16* vtb    = (u16*)(ws + (56u << 20));   // rms_vt -> attn

    prep<<<3072, 256, 0, stream>>>(x, Wqkv, Wout, xb, wqkvt, woutt);
    gemm_bf16<<<dim3(24, 32), 256, 0, stream>>>(xb, wqkvt, bqkv, qkvb, M_, 3072, 1024, 1);
    rms_vt<<<2048, 256, 0, stream>>>(qkvb, gq, gk, qbuf, kbuf, vtb);
    attn_mfma<<<2048, 256, 0, stream>>>(qbuf, kbuf, vtb, op012, op3, lsums);
    attn_combine<<<1024, 256, 0, stream>>>(op012, op3, lsums, attnb);
    gemm64<<<dim3(16, 64), 256, 0, stream>>>(attnb, woutt, bout, out, M_, 1024, 1024);
}